// Round 21
// baseline (109.241 us; speedup 1.0000x reference)
//
#include <hip/hip_runtime.h>

// Problem constants (fixed by the reference)
#define N_NODES   100000
#define N_EDGES   1600000
#define IN_CH     16
#define HID_CH    64
#define OUT_CH    128
#define N_GRAPHS  128

#define CAPS  4096                          // agg1 slots (expected ~2.3K)
#define BM_WORDS ((N_NODES + 31) / 32)      // 3125
#define BM_PAD   3200

#define NBLK   512                          // 2 blocks/CU (R19-validated)
#define GROUPS 32
#define GSIZE  (NBLK / GROUPS)
#define SCAN_CHUNK 3128                     // 4-aligned; 512*3128 >= N_EDGES
#define SCAN_V   (SCAN_CHUNK / 4)

#define R2CAP 64                            // list2 entries per block region (exp ~4)
#define R1CAP 512                           // list1 entries per block region (exp ~68)

typedef int      iv4 __attribute__((ext_vector_type(4)));
typedef float    fv4 __attribute__((ext_vector_type(4)));

// agent-scope load (memory-side) — ONLY for data crossing the in-kernel barrier
__device__ __forceinline__ float afload(const float* p) {
    return __hip_atomic_load(p, __ATOMIC_RELAXED, __HIP_MEMORY_SCOPE_AGENT);
}

// ---- tree barrier state (zeroed by k_p1 block 0; R13-validated relaxed form) ----
struct GBar { int leaf[GROUPS * 16]; int root[16]; int rootrel[16]; int leafrel[GROUPS * 16]; };
#define BAR_INTS ((int)(sizeof(GBar) / 4))

struct P {
    const float* x; const int* src; const int* dst; const int* ptr;
    const float* W1; const float* b1; const float* W2; const float* b2;
    float* out;
    unsigned* deg; int* map1;
    int* s1; int* d1; int* c1;              // list1 regions (np2 -> D)
    int* s2; int* d2; int* c2;              // list2 regions (p1 -> np2,E)
    float* agg1; unsigned* ndbm; GBar* bar;
};

__device__ __forceinline__ void gbar(GBar* b, int k) {
    asm volatile("s_waitcnt vmcnt(0) lgkmcnt(0)" ::: "memory");
    __syncthreads();
    if (threadIdx.x == 0) {
        int g = blockIdx.x / GSIZE;
        int a = __hip_atomic_fetch_add(&b->leaf[g * 16], 1, __ATOMIC_RELAXED,
                                       __HIP_MEMORY_SCOPE_AGENT);
        if (a == GSIZE * k - 1) {
            int r = __hip_atomic_fetch_add(&b->root[0], 1, __ATOMIC_RELAXED,
                                           __HIP_MEMORY_SCOPE_AGENT);
            if (r == GROUPS * k - 1) {
                __hip_atomic_store(&b->rootrel[0], k, __ATOMIC_RELAXED,
                                   __HIP_MEMORY_SCOPE_AGENT);
            } else {
                while (__hip_atomic_load(&b->rootrel[0], __ATOMIC_RELAXED,
                                         __HIP_MEMORY_SCOPE_AGENT) < k)
                    __builtin_amdgcn_s_sleep(2);
            }
            __hip_atomic_store(&b->leafrel[g * 16], k, __ATOMIC_RELAXED,
                               __HIP_MEMORY_SCOPE_AGENT);
        } else {
            while (__hip_atomic_load(&b->leafrel[g * 16], __ATOMIC_RELAXED,
                                     __HIP_MEMORY_SCOPE_AGENT) < k)
                __builtin_amdgcn_s_sleep(2);
        }
    }
    __syncthreads();
}

// ---------------- kernels ----------------
// Dispatch boundaries provide cross-kernel visibility (validated R5-R19).
// Per-block list regions + unconditional count stores: NO global counters,
// NO zero-prep dispatch.

// p1: LDS central bitmap from ptr; scan chunk; central-dst edges -> (s2,d2)
// region + c2[b]. Also zeroes deg/ndbm (block-strided) and bar (block 0).
__global__ void __launch_bounds__(256) k_p1(P p) {
    __shared__ unsigned cbm[3136];
    __shared__ int lbs[R2CAP], lbd[R2CAP];
    __shared__ int scnt;
    for (int t = threadIdx.x; t < 3136; t += blockDim.x) cbm[t] = 0u;
    if (threadIdx.x == 0) scnt = 0;
    __syncthreads();
    if (threadIdx.x < N_GRAPHS) {
        int c = p.ptr[threadIdx.x];
        atomicOr(&cbm[c >> 5], 1u << (c & 31));
    }
    // distributed init (none of these used by p1 logic)
    int gid = blockIdx.x * blockDim.x + threadIdx.x;
    int gst = gridDim.x * blockDim.x;
    iv4 z = {0, 0, 0, 0};
    for (int n = gid; n < N_NODES / 4; n += gst) ((iv4*)p.deg)[n] = z;
    for (int n = gid; n < BM_PAD / 4; n += gst) ((iv4*)p.ndbm)[n] = z;
    if (blockIdx.x == 0)
        for (int t = threadIdx.x; t < BAR_INTS; t += blockDim.x)
            ((int*)p.bar)[t] = 0;
    __syncthreads();
    int e0 = blockIdx.x * SCAN_CHUNK;
    for (int t = threadIdx.x; t < SCAN_V; t += blockDim.x) {
        int e = e0 + t * 4;
        if (e < N_EDGES) {
            iv4 d4 = *(const iv4*)(p.dst + e);
#pragma unroll
            for (int k = 0; k < 4; ++k) {
                int d = d4[k];
                if ((cbm[d >> 5] >> (d & 31)) & 1u) {
                    int idx = atomicAdd(&scnt, 1);
                    if (idx < R2CAP) { lbs[idx] = p.src[e + k]; lbd[idx] = d; }
                }
            }
        }
    }
    __syncthreads();
    int cnt = min(scnt, R2CAP);
    if (threadIdx.x == 0) p.c2[blockIdx.x] = cnt;     // unconditional store
    if ((int)threadIdx.x < cnt) {
        p.s2[blockIdx.x * R2CAP + threadIdx.x] = lbs[threadIdx.x];
        p.d2[blockIdx.x * R2CAP + threadIdx.x] = lbd[threadIdx.x];
    }
}

// np2: rebuild marked set in LDS from (ptr, s2 regions); block 0 compacts
// marked -> map1 slots and ORs marked words into ndbm (distributed across
// blocks); scan: marked-dst edges -> (s1,d1) region + c1[b], srcs -> ndbm.
// Also zeroes agg1 and inits out=b2.
__global__ void __launch_bounds__(256) k_np2(P p) {
    __shared__ unsigned bm[3136];
    __shared__ int ls[R1CAP], ld[R1CAP];
    __shared__ int c2l[NBLK];
    __shared__ int scnt, slotc;
    for (int t = threadIdx.x; t < 3136; t += blockDim.x) bm[t] = 0u;
    for (int t = threadIdx.x; t < NBLK; t += blockDim.x) c2l[t] = p.c2[t];
    if (threadIdx.x == 0) { scnt = 0; slotc = 0; }
    __syncthreads();
    if (threadIdx.x < N_GRAPHS) {
        int c = p.ptr[threadIdx.x];
        atomicOr(&bm[c >> 5], 1u << (c & 31));
    }
    for (int r = threadIdx.x; r < NBLK; r += blockDim.x) {
        int n = c2l[r];
        for (int i = 0; i < n; ++i) {
            int s = p.s2[r * R2CAP + i];
            atomicOr(&bm[s >> 5], 1u << (s & 31));
        }
    }
    // distributed init (first used by D / E)
    int gid = blockIdx.x * blockDim.x + threadIdx.x;
    int gst = gridDim.x * blockDim.x;
    for (int n = gid; n < (CAPS * IN_CH) / 4; n += gst)
        ((fv4*)p.agg1)[n] = (fv4){0.f, 0.f, 0.f, 0.f};
    for (int n = gid; n < (N_GRAPHS * OUT_CH) / 4; n += gst) {
        int c = (n * 4) & 127;
        ((fv4*)p.out)[n] = (fv4){ p.b2[c], p.b2[c + 1], p.b2[c + 2], p.b2[c + 3] };
    }
    __syncthreads();

    // marked words -> ndbm: distributed, ~6 words per block
    {
        int wpb = (BM_WORDS + NBLK - 1) / NBLK;     // 7
        for (int w = blockIdx.x * wpb + threadIdx.x;
             w < min((int)((blockIdx.x + 1) * wpb), BM_WORDS); w += blockDim.x) {
            unsigned word = bm[w];
            if (word) atomicOr(&p.ndbm[w], word);
        }
    }

    // block 0: compact marked nodes -> map1 slots (wave-aggregated, LDS counter)
    if (blockIdx.x == 0) {
        int lane = threadIdx.x & 63;
        for (int it = 0; it < 13; ++it) {
            int w = threadIdx.x + it * 256;
            unsigned word = (w < BM_WORDS) ? bm[w] : 0u;
            int c = __popc(word);
            int inc = c;
            for (int off = 1; off < 64; off <<= 1) {
                int t = __shfl_up(inc, off, 64);
                if (lane >= off) inc += t;
            }
            int total = __shfl(inc, 63, 64);
            int base = 0;
            if (total > 0) {
                if (lane == 63) base = atomicAdd(&slotc, total);
                base = __shfl(base, 63, 64);
                int slot = base + inc - c;
                unsigned ww = word;
                while (ww) {
                    int b = __ffs(ww) - 1; ww &= ww - 1;
                    int n = (w << 5) + b;
                    p.map1[n] = (slot < CAPS) ? slot : 0;
                    ++slot;
                }
            }
        }
    }

    // scan: marked-dst edges -> LDS buffers; srcs -> ndbm
    int e0 = blockIdx.x * SCAN_CHUNK;
    for (int t = threadIdx.x; t < SCAN_V; t += blockDim.x) {
        int e = e0 + t * 4;
        if (e < N_EDGES) {
            iv4 d4 = *(const iv4*)(p.dst + e);
#pragma unroll
            for (int k = 0; k < 4; ++k) {
                int d = d4[k];
                if ((bm[d >> 5] >> (d & 31)) & 1u) {
                    int s = p.src[e + k];
                    atomicOr(&p.ndbm[s >> 5], 1u << (s & 31));
                    int idx = atomicAdd(&scnt, 1);
                    if (idx < R1CAP) { ls[idx] = s; ld[idx] = d; }
                }
            }
        }
    }
    __syncthreads();
    int cnt = min(scnt, R1CAP);
    if (threadIdx.x == 0) p.c1[blockIdx.x] = cnt;     // unconditional store
    for (int t = threadIdx.x; t < cnt; t += blockDim.x) {
        p.s1[blockIdx.x * R1CAP + t] = ls[t];
        p.d1[blockIdx.x * R1CAP + t] = ld[t];
    }
}

// p3: snapshot ndbm (cached); degree count only for dst in the needed set.
__global__ void __launch_bounds__(256) k_p3(P p) {
    __shared__ unsigned nds[3136];
    for (int t = threadIdx.x; t < 3136 / 4; t += blockDim.x)
        ((iv4*)nds)[t] = ((const iv4*)p.ndbm)[t];
    __syncthreads();
    int e0 = blockIdx.x * SCAN_CHUNK;
    for (int t = threadIdx.x; t < SCAN_V; t += blockDim.x) {
        int e = e0 + t * 4;
        if (e < N_EDGES) {
            iv4 d4 = *(const iv4*)(p.dst + e);
#pragma unroll
            for (int k = 0; k < 4; ++k) {
                int d = d4[k];
                if ((nds[d >> 5] >> (d & 31)) & 1u) atomicAdd(&p.deg[d], 1u);
            }
        }
    }
}

// Phase D: agg1[slot(dst)] += dis[src]*x[src] over list1 regions.
// 4 waves per region; wave = 4 edges x 16 channels. All loads cached
// (inputs finalized in earlier dispatches).
__device__ void ph_D(const P& p) {
    int lane = threadIdx.x & 63;
    int g = lane >> 4;
    int c = lane & 15;
    int wid = blockIdx.x * (blockDim.x >> 6) + (threadIdx.x >> 6);
    int r = wid & (NBLK - 1);
    int sub = wid >> 9;                     // 0..3
    int c1r = p.c1[r];
    for (int i0 = sub * 4; i0 < c1r; i0 += 16) {
        int i = i0 + g;
        if (i < c1r) {
            int s = p.s1[r * R1CAP + i];
            int d = p.d1[r * R1CAP + i];
            int slot = p.map1[d];
            float w = rsqrtf((float)(1u + p.deg[s]));
            float xv = p.x[(size_t)s * IN_CH + c];
            atomicAdd(&p.agg1[(size_t)slot * IN_CH + c], w * xv);
        }
    }
}

// Phase E: per item (list2-region edge or central self), recompute
// h1relu from agg1 (afload — crosses the in-kernel barrier), W2 GEMV,
// atomics into out. Ballot row resolution; duplicates each accumulate.
__device__ void ph_E(const P& p) {
    __shared__ float w1s[IN_CH * HID_CH];
    __shared__ float b1s[HID_CH];
    __shared__ float w2s[HID_CH * OUT_CH];
    __shared__ int cent[128];
    __shared__ int c2l[NBLK];
    for (int t = threadIdx.x; t < IN_CH * HID_CH; t += blockDim.x) w1s[t] = p.W1[t];
    if (threadIdx.x < HID_CH) b1s[threadIdx.x] = p.b1[threadIdx.x];
    for (int t = threadIdx.x; t < HID_CH * OUT_CH; t += blockDim.x) w2s[t] = p.W2[t];
    if (threadIdx.x < 128) cent[threadIdx.x] = p.ptr[threadIdx.x];
    for (int t = threadIdx.x; t < NBLK; t += blockDim.x) c2l[t] = p.c2[t];
    __syncthreads();
    int lane = threadIdx.x & 63;
    int c0 = cent[lane];
    int c1v = cent[lane + 64];
    int wid = blockIdx.x * (blockDim.x >> 6) + (threadIdx.x >> 6);
    int nw = gridDim.x * (blockDim.x >> 6);
    for (int u = wid; u < NBLK + N_GRAPHS; u += nw) {
        int nE = (u < NBLK) ? c2l[u] : 1;
        for (int i = 0; i < nE; ++i) {
            int s, d, selfrow = -1;
            if (u < NBLK) {
                s = p.s2[u * R2CAP + i];
                d = p.d2[u * R2CAP + i];
            } else {
                selfrow = u - NBLK;
                s = cent[selfrow]; d = s;
            }
            int slot = p.map1[s];
            float dis_s = rsqrtf((float)(1u + p.deg[s]));
            float dis_d = rsqrtf((float)(1u + p.deg[d]));
            float norm = dis_s * dis_d;
            float vc = 0.0f;
            if (lane < IN_CH)
                vc = dis_s * afload(&p.agg1[(size_t)slot * IN_CH + lane])
                   + dis_s * dis_s * p.x[(size_t)s * IN_CH + lane];
            float h = b1s[lane];
#pragma unroll
            for (int c = 0; c < IN_CH; ++c)
                h += __shfl(vc, c, 64) * w1s[c * HID_CH + lane];
            h = fmaxf(h, 0.0f);
            float a0 = 0.0f, a1 = 0.0f;
#pragma unroll 8
            for (int j = 0; j < HID_CH; ++j) {
                float hv = __shfl(h, j, 64);
                a0 += hv * w2s[j * OUT_CH + lane];
                a1 += hv * w2s[j * OUT_CH + lane + 64];
            }
            a0 *= norm; a1 *= norm;
            if (selfrow >= 0) {
                atomicAdd(&p.out[selfrow * OUT_CH + lane], a0);
                atomicAdd(&p.out[selfrow * OUT_CH + lane + 64], a1);
            } else {
                unsigned long long b0 = __ballot(c0 == d);
                unsigned long long b1 = __ballot(c1v == d);
                while (b0) {
                    int r = __ffsll((long long)b0) - 1; b0 &= b0 - 1;
                    atomicAdd(&p.out[r * OUT_CH + lane], a0);
                    atomicAdd(&p.out[r * OUT_CH + lane + 64], a1);
                }
                while (b1) {
                    int r = __ffsll((long long)b1) - 1 + 64; b1 &= b1 - 1;
                    atomicAdd(&p.out[r * OUT_CH + lane], a0);
                    atomicAdd(&p.out[r * OUT_CH + lane + 64], a1);
                }
            }
        }
    }
}

// Cooperative D+barrier+E (only agg1 crosses the barrier).
__global__ void __launch_bounds__(256) k_DE(P p) {
    ph_D(p);
    gbar(p.bar, 1);
    ph_E(p);
}

// Fallback standalone kernels.
__global__ void __launch_bounds__(256) k_D(P p) { ph_D(p); }
__global__ void __launch_bounds__(256) k_E(P p) { ph_E(p); }

// ---------------- launch ----------------

extern "C" void kernel_launch(void* const* d_in, const int* in_sizes, int n_in,
                              void* d_out, int out_size, void* d_ws, size_t ws_size,
                              hipStream_t stream) {
    P p;
    p.x   = (const float*)d_in[0];          // fp32 (validated)
    const int* edge = (const int*)d_in[1];  // int32 (validated)
    p.src = edge;
    p.dst = edge + N_EDGES;
    p.ptr = (const int*)d_in[2];
    p.W1  = (const float*)d_in[3];
    p.b1  = (const float*)d_in[4];
    p.W2  = (const float*)d_in[5];
    p.b2  = (const float*)d_in[6];
    p.out = (float*)d_out;

    char* q = (char*)d_ws;
    auto alloc = [&](size_t bytes) {
        char* r = q; q += (bytes + 255) & ~size_t(255); return r;
    };
    p.deg  = (unsigned*)alloc((size_t)N_NODES * 4);
    p.map1 = (int*)     alloc((size_t)N_NODES * 4);
    p.s1   = (int*)     alloc((size_t)NBLK * R1CAP * 4);
    p.d1   = (int*)     alloc((size_t)NBLK * R1CAP * 4);
    p.c1   = (int*)     alloc((size_t)NBLK * 4);
    p.s2   = (int*)     alloc((size_t)NBLK * R2CAP * 4);
    p.d2   = (int*)     alloc((size_t)NBLK * R2CAP * 4);
    p.c2   = (int*)     alloc((size_t)NBLK * 4);
    p.agg1 = (float*)   alloc((size_t)CAPS * IN_CH * 4);
    p.ndbm = (unsigned*)alloc((size_t)BM_PAD * 4);
    p.bar  = (GBar*)    alloc(sizeof(GBar));

    hipLaunchKernelGGL(k_p1,  dim3(NBLK), dim3(256), 0, stream, p);
    hipLaunchKernelGGL(k_np2, dim3(NBLK), dim3(256), 0, stream, p);
    hipLaunchKernelGGL(k_p3,  dim3(NBLK), dim3(256), 0, stream, p);

    void* args[] = { (void*)&p };
    hipError_t err = hipLaunchCooperativeKernel((const void*)k_DE,
                                                dim3(NBLK), dim3(256),
                                                args, 0, stream);
    if (err != hipSuccess) {
        (void)hipGetLastError();            // clear sticky error, use fallback
        hipLaunchKernelGGL(k_D, dim3(NBLK), dim3(256), 0, stream, p);
        hipLaunchKernelGGL(k_E, dim3(128),  dim3(256), 0, stream, p);
    }
}

// Round 22
// 85.215 us; speedup vs baseline: 1.2819x; 1.2819x over previous
//
#include <hip/hip_runtime.h>

// Problem constants (fixed by the reference)
#define N_NODES   100000
#define N_EDGES   1600000
#define IN_CH     16
#define HID_CH    64
#define OUT_CH    128
#define N_GRAPHS  128

#define CAPS  4096                          // agg1 slots (expected ~2.3K)
#define BM_WORDS ((N_NODES + 31) / 32)      // 3125
#define BM_PAD   3200

#define NBLK   512                          // 2 blocks/CU (R19-validated)
#define SCAN_CHUNK 3128                     // 4-aligned; 512*3128 >= N_EDGES
#define SCAN_V   (SCAN_CHUNK / 4)

#define R2CAP 64                            // list2 entries per block region (exp ~4)
#define R1CAP 512                           // list1 entries per block region (exp ~68)

typedef int      iv4 __attribute__((ext_vector_type(4)));
typedef float    fv4 __attribute__((ext_vector_type(4)));

struct P {
    const float* x; const int* src; const int* dst; const int* ptr;
    const float* W1; const float* b1; const float* W2; const float* b2;
    float* out;
    unsigned* deg; int* map1;
    int* s1; int* d1; int* c1;              // list1 regions (np2 -> D)
    int* s2; int* d2; int* c2;              // list2 regions (p1 -> np2,E)
    float* agg1; unsigned* ndbm;
};

// ---------------- kernels ----------------
// 5 plain dispatches; dispatch boundaries provide all cross-phase coherence
// (validated R5-R21, absmax 0). Plain cached accesses everywhere; atomics
// only for true aggregation (deg, agg1, out, LDS/global bitmap ORs).
// Coop launch abandoned: measured ~30us fixed overhead per coop dispatch
// (R20 k_mega, R21 k_DE) — always worse than a plain dispatch boundary.

// p1: LDS central bitmap from ptr; scan chunk; central-dst edges -> (s2,d2)
// region + c2[b] (unconditional store — no zeroing needed). Also zeroes
// deg/ndbm (block-strided; unused by p1's own logic).
__global__ void __launch_bounds__(256) k_p1(P p) {
    __shared__ unsigned cbm[3136];
    __shared__ int lbs[R2CAP], lbd[R2CAP];
    __shared__ int scnt;
    for (int t = threadIdx.x; t < 3136; t += blockDim.x) cbm[t] = 0u;
    if (threadIdx.x == 0) scnt = 0;
    __syncthreads();
    if (threadIdx.x < N_GRAPHS) {
        int c = p.ptr[threadIdx.x];
        atomicOr(&cbm[c >> 5], 1u << (c & 31));
    }
    // distributed init
    int gid = blockIdx.x * blockDim.x + threadIdx.x;
    int gst = gridDim.x * blockDim.x;
    iv4 z = {0, 0, 0, 0};
    for (int n = gid; n < N_NODES / 4; n += gst) ((iv4*)p.deg)[n] = z;
    for (int n = gid; n < BM_PAD / 4; n += gst) ((iv4*)p.ndbm)[n] = z;
    __syncthreads();
    int e0 = blockIdx.x * SCAN_CHUNK;
    for (int t = threadIdx.x; t < SCAN_V; t += blockDim.x) {
        int e = e0 + t * 4;
        if (e < N_EDGES) {
            iv4 d4 = *(const iv4*)(p.dst + e);
#pragma unroll
            for (int k = 0; k < 4; ++k) {
                int d = d4[k];
                if ((cbm[d >> 5] >> (d & 31)) & 1u) {
                    int idx = atomicAdd(&scnt, 1);
                    if (idx < R2CAP) { lbs[idx] = p.src[e + k]; lbd[idx] = d; }
                }
            }
        }
    }
    __syncthreads();
    int cnt = min(scnt, R2CAP);
    if (threadIdx.x == 0) p.c2[blockIdx.x] = cnt;
    if ((int)threadIdx.x < cnt) {
        p.s2[blockIdx.x * R2CAP + threadIdx.x] = lbs[threadIdx.x];
        p.d2[blockIdx.x * R2CAP + threadIdx.x] = lbd[threadIdx.x];
    }
}

// np2: rebuild marked set in LDS from (ptr, s2 regions); block 0 compacts
// marked -> map1 slots; marked words -> ndbm (distributed); scan: marked-dst
// edges -> (s1,d1) region + c1[b], srcs -> ndbm. Also zeroes agg1, out=b2.
__global__ void __launch_bounds__(256) k_np2(P p) {
    __shared__ unsigned bm[3136];
    __shared__ int ls[R1CAP], ld[R1CAP];
    __shared__ int c2l[NBLK];
    __shared__ int scnt, slotc;
    for (int t = threadIdx.x; t < 3136; t += blockDim.x) bm[t] = 0u;
    for (int t = threadIdx.x; t < NBLK; t += blockDim.x) c2l[t] = p.c2[t];
    if (threadIdx.x == 0) { scnt = 0; slotc = 0; }
    __syncthreads();
    if (threadIdx.x < N_GRAPHS) {
        int c = p.ptr[threadIdx.x];
        atomicOr(&bm[c >> 5], 1u << (c & 31));
    }
    for (int r = threadIdx.x; r < NBLK; r += blockDim.x) {
        int n = c2l[r];
        for (int i = 0; i < n; ++i) {
            int s = p.s2[r * R2CAP + i];
            atomicOr(&bm[s >> 5], 1u << (s & 31));
        }
    }
    // distributed init (first used by D / E)
    int gid = blockIdx.x * blockDim.x + threadIdx.x;
    int gst = gridDim.x * blockDim.x;
    for (int n = gid; n < (CAPS * IN_CH) / 4; n += gst)
        ((fv4*)p.agg1)[n] = (fv4){0.f, 0.f, 0.f, 0.f};
    for (int n = gid; n < (N_GRAPHS * OUT_CH) / 4; n += gst) {
        int c = (n * 4) & 127;
        ((fv4*)p.out)[n] = (fv4){ p.b2[c], p.b2[c + 1], p.b2[c + 2], p.b2[c + 3] };
    }
    __syncthreads();

    // marked words -> ndbm: distributed, ~7 words per block
    {
        int wpb = (BM_WORDS + NBLK - 1) / NBLK;
        for (int w = blockIdx.x * wpb + threadIdx.x;
             w < min((int)((blockIdx.x + 1) * wpb), BM_WORDS); w += blockDim.x) {
            unsigned word = bm[w];
            if (word) atomicOr(&p.ndbm[w], word);
        }
    }

    // block 0: compact marked nodes -> map1 slots (wave-aggregated, LDS counter)
    if (blockIdx.x == 0) {
        int lane = threadIdx.x & 63;
        for (int it = 0; it < 13; ++it) {
            int w = threadIdx.x + it * 256;
            unsigned word = (w < BM_WORDS) ? bm[w] : 0u;
            int c = __popc(word);
            int inc = c;
            for (int off = 1; off < 64; off <<= 1) {
                int t = __shfl_up(inc, off, 64);
                if (lane >= off) inc += t;
            }
            int total = __shfl(inc, 63, 64);
            int base = 0;
            if (total > 0) {
                if (lane == 63) base = atomicAdd(&slotc, total);
                base = __shfl(base, 63, 64);
                int slot = base + inc - c;
                unsigned ww = word;
                while (ww) {
                    int b = __ffs(ww) - 1; ww &= ww - 1;
                    int n = (w << 5) + b;
                    p.map1[n] = (slot < CAPS) ? slot : 0;
                    ++slot;
                }
            }
        }
    }

    // scan: marked-dst edges -> LDS buffers; srcs -> ndbm
    int e0 = blockIdx.x * SCAN_CHUNK;
    for (int t = threadIdx.x; t < SCAN_V; t += blockDim.x) {
        int e = e0 + t * 4;
        if (e < N_EDGES) {
            iv4 d4 = *(const iv4*)(p.dst + e);
#pragma unroll
            for (int k = 0; k < 4; ++k) {
                int d = d4[k];
                if ((bm[d >> 5] >> (d & 31)) & 1u) {
                    int s = p.src[e + k];
                    atomicOr(&p.ndbm[s >> 5], 1u << (s & 31));
                    int idx = atomicAdd(&scnt, 1);
                    if (idx < R1CAP) { ls[idx] = s; ld[idx] = d; }
                }
            }
        }
    }
    __syncthreads();
    int cnt = min(scnt, R1CAP);
    if (threadIdx.x == 0) p.c1[blockIdx.x] = cnt;
    for (int t = threadIdx.x; t < cnt; t += blockDim.x) {
        p.s1[blockIdx.x * R1CAP + t] = ls[t];
        p.d1[blockIdx.x * R1CAP + t] = ld[t];
    }
}

// p3: snapshot ndbm (cached); degree count only for dst in the needed set.
__global__ void __launch_bounds__(256) k_p3(P p) {
    __shared__ unsigned nds[3136];
    for (int t = threadIdx.x; t < 3136 / 4; t += blockDim.x)
        ((iv4*)nds)[t] = ((const iv4*)p.ndbm)[t];
    __syncthreads();
    int e0 = blockIdx.x * SCAN_CHUNK;
    for (int t = threadIdx.x; t < SCAN_V; t += blockDim.x) {
        int e = e0 + t * 4;
        if (e < N_EDGES) {
            iv4 d4 = *(const iv4*)(p.dst + e);
#pragma unroll
            for (int k = 0; k < 4; ++k) {
                int d = d4[k];
                if ((nds[d >> 5] >> (d & 31)) & 1u) atomicAdd(&p.deg[d], 1u);
            }
        }
    }
}

// D: agg1[slot(dst)] += dis[src]*x[src] over list1 regions.
// 4 waves per region; wave = 4 edges x 16 channels. All loads cached.
__global__ void __launch_bounds__(256) k_D(P p) {
    int lane = threadIdx.x & 63;
    int g = lane >> 4;
    int c = lane & 15;
    int wid = blockIdx.x * (blockDim.x >> 6) + (threadIdx.x >> 6);
    int r = wid & (NBLK - 1);
    int sub = wid >> 9;                     // 0..3
    int c1r = p.c1[r];
    for (int i0 = sub * 4; i0 < c1r; i0 += 16) {
        int i = i0 + g;
        if (i < c1r) {
            int s = p.s1[r * R1CAP + i];
            int d = p.d1[r * R1CAP + i];
            int slot = p.map1[d];
            float w = rsqrtf((float)(1u + p.deg[s]));
            float xv = p.x[(size_t)s * IN_CH + c];
            atomicAdd(&p.agg1[(size_t)slot * IN_CH + c], w * xv);
        }
    }
}

// E: per item (list2-region edge or central self), recompute
// h1relu = relu((dis_s*agg1[slot] + dis_s^2*x[s]) @ W1 + b1) in-register,
// W2 GEMV, atomics into out (bias pre-set). Ballot row resolution over the
// 128 central values; duplicate central rows each accumulate independently.
__global__ void __launch_bounds__(256) k_E(P p) {
    __shared__ float w1s[IN_CH * HID_CH];
    __shared__ float b1s[HID_CH];
    __shared__ float w2s[HID_CH * OUT_CH];
    __shared__ int cent[128];
    __shared__ int c2l[NBLK];
    for (int t = threadIdx.x; t < IN_CH * HID_CH; t += blockDim.x) w1s[t] = p.W1[t];
    if (threadIdx.x < HID_CH) b1s[threadIdx.x] = p.b1[threadIdx.x];
    for (int t = threadIdx.x; t < HID_CH * OUT_CH; t += blockDim.x) w2s[t] = p.W2[t];
    if (threadIdx.x < 128) cent[threadIdx.x] = p.ptr[threadIdx.x];
    for (int t = threadIdx.x; t < NBLK; t += blockDim.x) c2l[t] = p.c2[t];
    __syncthreads();
    int lane = threadIdx.x & 63;
    int c0 = cent[lane];
    int c1v = cent[lane + 64];
    int wid = blockIdx.x * (blockDim.x >> 6) + (threadIdx.x >> 6);
    int nw = gridDim.x * (blockDim.x >> 6);
    for (int u = wid; u < NBLK + N_GRAPHS; u += nw) {
        int nE = (u < NBLK) ? c2l[u] : 1;
        for (int i = 0; i < nE; ++i) {
            int s, d, selfrow = -1;
            if (u < NBLK) {
                s = p.s2[u * R2CAP + i];
                d = p.d2[u * R2CAP + i];
            } else {
                selfrow = u - NBLK;
                s = cent[selfrow]; d = s;
            }
            int slot = p.map1[s];
            float dis_s = rsqrtf((float)(1u + p.deg[s]));
            float dis_d = rsqrtf((float)(1u + p.deg[d]));
            float norm = dis_s * dis_d;
            float vc = 0.0f;
            if (lane < IN_CH)
                vc = dis_s * p.agg1[(size_t)slot * IN_CH + lane]
                   + dis_s * dis_s * p.x[(size_t)s * IN_CH + lane];
            float h = b1s[lane];
#pragma unroll
            for (int c = 0; c < IN_CH; ++c)
                h += __shfl(vc, c, 64) * w1s[c * HID_CH + lane];
            h = fmaxf(h, 0.0f);
            float a0 = 0.0f, a1 = 0.0f;
#pragma unroll 8
            for (int j = 0; j < HID_CH; ++j) {
                float hv = __shfl(h, j, 64);
                a0 += hv * w2s[j * OUT_CH + lane];
                a1 += hv * w2s[j * OUT_CH + lane + 64];
            }
            a0 *= norm; a1 *= norm;
            if (selfrow >= 0) {
                atomicAdd(&p.out[selfrow * OUT_CH + lane], a0);
                atomicAdd(&p.out[selfrow * OUT_CH + lane + 64], a1);
            } else {
                unsigned long long b0 = __ballot(c0 == d);
                unsigned long long b1 = __ballot(c1v == d);
                while (b0) {
                    int r = __ffsll((long long)b0) - 1; b0 &= b0 - 1;
                    atomicAdd(&p.out[r * OUT_CH + lane], a0);
                    atomicAdd(&p.out[r * OUT_CH + lane + 64], a1);
                }
                while (b1) {
                    int r = __ffsll((long long)b1) - 1 + 64; b1 &= b1 - 1;
                    atomicAdd(&p.out[r * OUT_CH + lane], a0);
                    atomicAdd(&p.out[r * OUT_CH + lane + 64], a1);
                }
            }
        }
    }
}

// ---------------- launch ----------------

extern "C" void kernel_launch(void* const* d_in, const int* in_sizes, int n_in,
                              void* d_out, int out_size, void* d_ws, size_t ws_size,
                              hipStream_t stream) {
    P p;
    p.x   = (const float*)d_in[0];          // fp32 (validated)
    const int* edge = (const int*)d_in[1];  // int32 (validated)
    p.src = edge;
    p.dst = edge + N_EDGES;
    p.ptr = (const int*)d_in[2];
    p.W1  = (const float*)d_in[3];
    p.b1  = (const float*)d_in[4];
    p.W2  = (const float*)d_in[5];
    p.b2  = (const float*)d_in[6];
    p.out = (float*)d_out;

    char* q = (char*)d_ws;
    auto alloc = [&](size_t bytes) {
        char* r = q; q += (bytes + 255) & ~size_t(255); return r;
    };
    p.deg  = (unsigned*)alloc((size_t)N_NODES * 4);
    p.map1 = (int*)     alloc((size_t)N_NODES * 4);
    p.s1   = (int*)     alloc((size_t)NBLK * R1CAP * 4);
    p.d1   = (int*)     alloc((size_t)NBLK * R1CAP * 4);
    p.c1   = (int*)     alloc((size_t)NBLK * 4);
    p.s2   = (int*)     alloc((size_t)NBLK * R2CAP * 4);
    p.d2   = (int*)     alloc((size_t)NBLK * R2CAP * 4);
    p.c2   = (int*)     alloc((size_t)NBLK * 4);
    p.agg1 = (float*)   alloc((size_t)CAPS * IN_CH * 4);
    p.ndbm = (unsigned*)alloc((size_t)BM_PAD * 4);

    // 5 plain dispatches — the minimum for the 5-deep dependency chain.
    hipLaunchKernelGGL(k_p1,  dim3(NBLK), dim3(256), 0, stream, p);
    hipLaunchKernelGGL(k_np2, dim3(NBLK), dim3(256), 0, stream, p);
    hipLaunchKernelGGL(k_p3,  dim3(NBLK), dim3(256), 0, stream, p);
    hipLaunchKernelGGL(k_D,   dim3(NBLK), dim3(256), 0, stream, p);
    hipLaunchKernelGGL(k_E,   dim3(160),  dim3(256), 0, stream, p);
}

// Round 23
// 69.847 us; speedup vs baseline: 1.5640x; 1.2200x over previous
//
#include <hip/hip_runtime.h>

// Problem constants (fixed by the reference)
#define N_NODES   100000
#define N_EDGES   1600000
#define IN_CH     16
#define HID_CH    64
#define OUT_CH    128
#define N_GRAPHS  128

#define CAPS  4096                          // agg1 slots (expected ~2.3K)
#define BM_WORDS ((N_NODES + 31) / 32)      // 3125
#define BM_PAD   3200

#define NBLK   512                          // 2 blocks/CU (R19-validated) for scans
#define SCAN_CHUNK 3128                     // 4-aligned; 512*3128 >= N_EDGES
#define SCAN_V   (SCAN_CHUNK / 4)

#define R2CAP 64                            // list2 entries per block region (exp ~4, max ~12)
#define R1CAP 512                           // list1 entries per block region (exp ~68)

typedef int      iv4 __attribute__((ext_vector_type(4)));
typedef float    fv4 __attribute__((ext_vector_type(4)));

struct P {
    const float* x; const int* src; const int* dst; const int* ptr;
    const float* W1; const float* b1; const float* W2; const float* b2;
    float* out;
    unsigned* deg; int* map1;
    int* s1; int* d1; int* c1;              // list1 regions (np2 -> D)
    int* s2; int* d2; int* c2;              // list2 regions (p1 -> np2,E)
    float* agg1; unsigned* ndbm;
};

// ---------------- kernels ----------------
// 5 plain dispatches; dispatch boundaries provide all cross-phase coherence
// (validated R5-R22, absmax 0). Coop launch abandoned (~30us fixed overhead
// measured R20/R21). Latency-tail lesson (R22): never let one wave own a
// region's items serially — stripe items across waves.

// p1: LDS central bitmap from ptr; scan chunk; central-dst edges -> (s2,d2)
// region + c2[b]. Also zeroes deg/ndbm (block-strided).
__global__ void __launch_bounds__(256) k_p1(P p) {
    __shared__ unsigned cbm[3136];
    __shared__ int lbs[R2CAP], lbd[R2CAP];
    __shared__ int scnt;
    for (int t = threadIdx.x; t < 3136; t += blockDim.x) cbm[t] = 0u;
    if (threadIdx.x == 0) scnt = 0;
    __syncthreads();
    if (threadIdx.x < N_GRAPHS) {
        int c = p.ptr[threadIdx.x];
        atomicOr(&cbm[c >> 5], 1u << (c & 31));
    }
    int gid = blockIdx.x * blockDim.x + threadIdx.x;
    int gst = gridDim.x * blockDim.x;
    iv4 z = {0, 0, 0, 0};
    for (int n = gid; n < N_NODES / 4; n += gst) ((iv4*)p.deg)[n] = z;
    for (int n = gid; n < BM_PAD / 4; n += gst) ((iv4*)p.ndbm)[n] = z;
    __syncthreads();
    int e0 = blockIdx.x * SCAN_CHUNK;
    for (int t = threadIdx.x; t < SCAN_V; t += blockDim.x) {
        int e = e0 + t * 4;
        if (e < N_EDGES) {
            iv4 d4 = *(const iv4*)(p.dst + e);
#pragma unroll
            for (int k = 0; k < 4; ++k) {
                int d = d4[k];
                if ((cbm[d >> 5] >> (d & 31)) & 1u) {
                    int idx = atomicAdd(&scnt, 1);
                    if (idx < R2CAP) { lbs[idx] = p.src[e + k]; lbd[idx] = d; }
                }
            }
        }
    }
    __syncthreads();
    int cnt = min(scnt, R2CAP);
    if (threadIdx.x == 0) p.c2[blockIdx.x] = cnt;
    if ((int)threadIdx.x < cnt) {
        p.s2[blockIdx.x * R2CAP + threadIdx.x] = lbs[threadIdx.x];
        p.d2[blockIdx.x * R2CAP + threadIdx.x] = lbd[threadIdx.x];
    }
}

// np2: rebuild marked set in LDS from (ptr, s2 regions); block 0 compacts
// marked -> map1 slots; marked words -> ndbm (distributed); scan: marked-dst
// edges -> (s1,d1) region + c1[b], srcs -> ndbm. Also zeroes agg1, out=b2.
__global__ void __launch_bounds__(256) k_np2(P p) {
    __shared__ unsigned bm[3136];
    __shared__ int ls[R1CAP], ld[R1CAP];
    __shared__ int c2l[NBLK];
    __shared__ int scnt, slotc;
    for (int t = threadIdx.x; t < 3136; t += blockDim.x) bm[t] = 0u;
    for (int t = threadIdx.x; t < NBLK; t += blockDim.x) c2l[t] = p.c2[t];
    if (threadIdx.x == 0) { scnt = 0; slotc = 0; }
    __syncthreads();
    if (threadIdx.x < N_GRAPHS) {
        int c = p.ptr[threadIdx.x];
        atomicOr(&bm[c >> 5], 1u << (c & 31));
    }
    for (int r = threadIdx.x; r < NBLK; r += blockDim.x) {
        int n = c2l[r];
        for (int i = 0; i < n; ++i) {
            int s = p.s2[r * R2CAP + i];
            atomicOr(&bm[s >> 5], 1u << (s & 31));
        }
    }
    int gid = blockIdx.x * blockDim.x + threadIdx.x;
    int gst = gridDim.x * blockDim.x;
    for (int n = gid; n < (CAPS * IN_CH) / 4; n += gst)
        ((fv4*)p.agg1)[n] = (fv4){0.f, 0.f, 0.f, 0.f};
    for (int n = gid; n < (N_GRAPHS * OUT_CH) / 4; n += gst) {
        int c = (n * 4) & 127;
        ((fv4*)p.out)[n] = (fv4){ p.b2[c], p.b2[c + 1], p.b2[c + 2], p.b2[c + 3] };
    }
    __syncthreads();

    {
        int wpb = (BM_WORDS + NBLK - 1) / NBLK;
        for (int w = blockIdx.x * wpb + threadIdx.x;
             w < min((int)((blockIdx.x + 1) * wpb), BM_WORDS); w += blockDim.x) {
            unsigned word = bm[w];
            if (word) atomicOr(&p.ndbm[w], word);
        }
    }

    if (blockIdx.x == 0) {
        int lane = threadIdx.x & 63;
        for (int it = 0; it < 13; ++it) {
            int w = threadIdx.x + it * 256;
            unsigned word = (w < BM_WORDS) ? bm[w] : 0u;
            int c = __popc(word);
            int inc = c;
            for (int off = 1; off < 64; off <<= 1) {
                int t = __shfl_up(inc, off, 64);
                if (lane >= off) inc += t;
            }
            int total = __shfl(inc, 63, 64);
            int base = 0;
            if (total > 0) {
                if (lane == 63) base = atomicAdd(&slotc, total);
                base = __shfl(base, 63, 64);
                int slot = base + inc - c;
                unsigned ww = word;
                while (ww) {
                    int b = __ffs(ww) - 1; ww &= ww - 1;
                    int n = (w << 5) + b;
                    p.map1[n] = (slot < CAPS) ? slot : 0;
                    ++slot;
                }
            }
        }
    }

    int e0 = blockIdx.x * SCAN_CHUNK;
    for (int t = threadIdx.x; t < SCAN_V; t += blockDim.x) {
        int e = e0 + t * 4;
        if (e < N_EDGES) {
            iv4 d4 = *(const iv4*)(p.dst + e);
#pragma unroll
            for (int k = 0; k < 4; ++k) {
                int d = d4[k];
                if ((bm[d >> 5] >> (d & 31)) & 1u) {
                    int s = p.src[e + k];
                    atomicOr(&p.ndbm[s >> 5], 1u << (s & 31));
                    int idx = atomicAdd(&scnt, 1);
                    if (idx < R1CAP) { ls[idx] = s; ld[idx] = d; }
                }
            }
        }
    }
    __syncthreads();
    int cnt = min(scnt, R1CAP);
    if (threadIdx.x == 0) p.c1[blockIdx.x] = cnt;
    for (int t = threadIdx.x; t < cnt; t += blockDim.x) {
        p.s1[blockIdx.x * R1CAP + t] = ls[t];
        p.d1[blockIdx.x * R1CAP + t] = ld[t];
    }
}

// p3: snapshot ndbm (cached); degree count only for dst in the needed set.
__global__ void __launch_bounds__(256) k_p3(P p) {
    __shared__ unsigned nds[3136];
    for (int t = threadIdx.x; t < 3136 / 4; t += blockDim.x)
        ((iv4*)nds)[t] = ((const iv4*)p.ndbm)[t];
    __syncthreads();
    int e0 = blockIdx.x * SCAN_CHUNK;
    for (int t = threadIdx.x; t < SCAN_V; t += blockDim.x) {
        int e = e0 + t * 4;
        if (e < N_EDGES) {
            iv4 d4 = *(const iv4*)(p.dst + e);
#pragma unroll
            for (int k = 0; k < 4; ++k) {
                int d = d4[k];
                if ((nds[d >> 5] >> (d & 31)) & 1u) atomicAdd(&p.deg[d], 1u);
            }
        }
    }
}

// D: agg1[slot(dst)] += dis[src]*x[src] over list1 regions.
// 1024 blocks -> 4096 waves: 8 stripes per region (R22 tail fix).
// Wave iteration = 4 edges (groups) x 16 channels; stride 32.
__global__ void __launch_bounds__(256) k_D(P p) {
    int lane = threadIdx.x & 63;
    int g = lane >> 4;
    int c = lane & 15;
    int wid = blockIdx.x * (blockDim.x >> 6) + (threadIdx.x >> 6);
    int r = wid & (NBLK - 1);
    int sub = wid >> 9;                     // 0..7
    int c1r = p.c1[r];
    for (int i0 = sub * 4; i0 < c1r; i0 += 32) {
        int i = i0 + g;
        if (i < c1r) {
            int s = p.s1[r * R1CAP + i];
            int d = p.d1[r * R1CAP + i];
            int slot = p.map1[d];
            float w = rsqrtf((float)(1u + p.deg[s]));
            float xv = p.x[(size_t)s * IN_CH + c];
            atomicAdd(&p.agg1[(size_t)slot * IN_CH + c], w * xv);
        }
    }
}

// E item processor: h1relu = relu((dis_s*agg1[slot] + dis_s^2*x[s])@W1 + b1),
// then W2 GEMV; atomic accumulate into out rows (ballot row resolution for
// edge items — duplicate central rows each accumulate; self items use their row).
__device__ __forceinline__ void e_item(const P& p, const float* w1s,
                                       const float* b1s, const float* w2s,
                                       int lane, int c0, int c1v,
                                       int s, int d, int selfrow) {
    int slot = p.map1[s];
    float dis_s = rsqrtf((float)(1u + p.deg[s]));
    float dis_d = rsqrtf((float)(1u + p.deg[d]));
    float norm = dis_s * dis_d;
    float vc = 0.0f;
    if (lane < IN_CH)
        vc = dis_s * p.agg1[(size_t)slot * IN_CH + lane]
           + dis_s * dis_s * p.x[(size_t)s * IN_CH + lane];
    float h = b1s[lane];
#pragma unroll
    for (int c = 0; c < IN_CH; ++c)
        h += __shfl(vc, c, 64) * w1s[c * HID_CH + lane];
    h = fmaxf(h, 0.0f);
    float a0 = 0.0f, a1 = 0.0f;
#pragma unroll 8
    for (int j = 0; j < HID_CH; ++j) {
        float hv = __shfl(h, j, 64);
        a0 += hv * w2s[j * OUT_CH + lane];
        a1 += hv * w2s[j * OUT_CH + lane + 64];
    }
    a0 *= norm; a1 *= norm;
    if (selfrow >= 0) {
        atomicAdd(&p.out[selfrow * OUT_CH + lane], a0);
        atomicAdd(&p.out[selfrow * OUT_CH + lane + 64], a1);
    } else {
        unsigned long long b0 = __ballot(c0 == d);
        unsigned long long b1 = __ballot(c1v == d);
        while (b0) {
            int r = __ffsll((long long)b0) - 1; b0 &= b0 - 1;
            atomicAdd(&p.out[r * OUT_CH + lane], a0);
            atomicAdd(&p.out[r * OUT_CH + lane + 64], a1);
        }
        while (b1) {
            int r = __ffsll((long long)b1) - 1 + 64; b1 &= b1 - 1;
            atomicAdd(&p.out[r * OUT_CH + lane], a0);
            atomicAdd(&p.out[r * OUT_CH + lane + 64], a1);
        }
    }
}

// E: 1024 blocks -> 4096 waves; wave = (region u = wid&511, stripe wid>>9),
// items i = stripe, stripe+8, ... (<=2 serial chains for max region ~12).
// Waves 0..127 additionally handle the 128 central self items.
__global__ void __launch_bounds__(256) k_E(P p) {
    __shared__ float w1s[IN_CH * HID_CH];
    __shared__ float b1s[HID_CH];
    __shared__ float w2s[HID_CH * OUT_CH];
    __shared__ int cent[128];
    for (int t = threadIdx.x; t < IN_CH * HID_CH; t += blockDim.x) w1s[t] = p.W1[t];
    if (threadIdx.x < HID_CH) b1s[threadIdx.x] = p.b1[threadIdx.x];
    for (int t = threadIdx.x; t < HID_CH * OUT_CH; t += blockDim.x) w2s[t] = p.W2[t];
    if (threadIdx.x < 128) cent[threadIdx.x] = p.ptr[threadIdx.x];
    __syncthreads();
    int lane = threadIdx.x & 63;
    int c0 = cent[lane];
    int c1v = cent[lane + 64];
    int wid = blockIdx.x * (blockDim.x >> 6) + (threadIdx.x >> 6);   // 0..4095
    int u = wid & (NBLK - 1);
    int stripe = wid >> 9;                  // 0..7
    int nE = p.c2[u];
    for (int i = stripe; i < nE; i += 8)
        e_item(p, w1s, b1s, w2s, lane, c0, c1v,
               p.s2[u * R2CAP + i], p.d2[u * R2CAP + i], -1);
    if (wid < N_GRAPHS)
        e_item(p, w1s, b1s, w2s, lane, c0, c1v, cent[wid], cent[wid], wid);
}

// ---------------- launch ----------------

extern "C" void kernel_launch(void* const* d_in, const int* in_sizes, int n_in,
                              void* d_out, int out_size, void* d_ws, size_t ws_size,
                              hipStream_t stream) {
    P p;
    p.x   = (const float*)d_in[0];          // fp32 (validated)
    const int* edge = (const int*)d_in[1];  // int32 (validated)
    p.src = edge;
    p.dst = edge + N_EDGES;
    p.ptr = (const int*)d_in[2];
    p.W1  = (const float*)d_in[3];
    p.b1  = (const float*)d_in[4];
    p.W2  = (const float*)d_in[5];
    p.b2  = (const float*)d_in[6];
    p.out = (float*)d_out;

    char* q = (char*)d_ws;
    auto alloc = [&](size_t bytes) {
        char* r = q; q += (bytes + 255) & ~size_t(255); return r;
    };
    p.deg  = (unsigned*)alloc((size_t)N_NODES * 4);
    p.map1 = (int*)     alloc((size_t)N_NODES * 4);
    p.s1   = (int*)     alloc((size_t)NBLK * R1CAP * 4);
    p.d1   = (int*)     alloc((size_t)NBLK * R1CAP * 4);
    p.c1   = (int*)     alloc((size_t)NBLK * 4);
    p.s2   = (int*)     alloc((size_t)NBLK * R2CAP * 4);
    p.d2   = (int*)     alloc((size_t)NBLK * R2CAP * 4);
    p.c2   = (int*)     alloc((size_t)NBLK * 4);
    p.agg1 = (float*)   alloc((size_t)CAPS * IN_CH * 4);
    p.ndbm = (unsigned*)alloc((size_t)BM_PAD * 4);

    hipLaunchKernelGGL(k_p1,  dim3(NBLK), dim3(256), 0, stream, p);
    hipLaunchKernelGGL(k_np2, dim3(NBLK), dim3(256), 0, stream, p);
    hipLaunchKernelGGL(k_p3,  dim3(NBLK), dim3(256), 0, stream, p);
    hipLaunchKernelGGL(k_D,   dim3(1024), dim3(256), 0, stream, p);
    hipLaunchKernelGGL(k_E,   dim3(1024), dim3(256), 0, stream, p);
}

// Round 24
// 61.855 us; speedup vs baseline: 1.7661x; 1.1292x over previous
//
#include <hip/hip_runtime.h>

// Problem constants (fixed by the reference)
#define N_NODES   100000
#define N_EDGES   1600000
#define IN_CH     16
#define HID_CH    64
#define OUT_CH    128
#define N_GRAPHS  128

#define CAPS  4096                          // agg1 slots (expected ~2.3K)
#define BM_WORDS ((N_NODES + 31) / 32)      // 3125
#define BM_PAD   3200

#define NBLK   512                          // scan grid (R19-validated ramp optimum)
#define SBLK   1024                         // scan block size: 32 waves/CU occupancy
#define SCAN_CHUNK 3128                     // 4-aligned; 512*3128 >= N_EDGES
#define SCAN_V   (SCAN_CHUNK / 4)

#define R2CAP 64                            // list2 entries per region (exp ~4, max ~12)
#define R1CAP 512                           // list1 entries per region (exp ~68)

typedef int      iv4 __attribute__((ext_vector_type(4)));
typedef float    fv4 __attribute__((ext_vector_type(4)));

struct P {
    const float* x; const int* src; const int* dst; const int* ptr;
    const float* W1; const float* b1; const float* W2; const float* b2;
    float* out;
    unsigned* deg; int* map1;
    int* s1; int* d1; int* c1;              // list1 regions (np2 -> D)
    int* s2; int* d2; int* c2;              // list2 regions (p1 -> np2,E)
    float* agg1; unsigned* ndbm;
};

// ---------------- kernels ----------------
// 5 plain dispatches; dispatch boundaries provide all cross-phase coherence
// (validated R5-R23, absmax 0). Coop launch abandoned (~30us fixed overhead,
// R20/R21). Latency lessons: stripe region items across waves (R22->R23);
// scans need max wave occupancy (this round).

// p1: LDS central bitmap from ptr; scan chunk; central-dst edges -> (s2,d2)
// region + c2[b]. Also zeroes deg/ndbm (block-strided).
__global__ void __launch_bounds__(SBLK) k_p1(P p) {
    __shared__ unsigned cbm[3136];
    __shared__ int lbs[R2CAP], lbd[R2CAP];
    __shared__ int scnt;
    for (int t = threadIdx.x; t < 3136; t += blockDim.x) cbm[t] = 0u;
    if (threadIdx.x == 0) scnt = 0;
    __syncthreads();
    if (threadIdx.x < N_GRAPHS) {
        int c = p.ptr[threadIdx.x];
        atomicOr(&cbm[c >> 5], 1u << (c & 31));
    }
    int gid = blockIdx.x * blockDim.x + threadIdx.x;
    int gst = gridDim.x * blockDim.x;
    iv4 z = {0, 0, 0, 0};
    for (int n = gid; n < N_NODES / 4; n += gst) ((iv4*)p.deg)[n] = z;
    for (int n = gid; n < BM_PAD / 4; n += gst) ((iv4*)p.ndbm)[n] = z;
    __syncthreads();
    int e0 = blockIdx.x * SCAN_CHUNK;
    for (int t = threadIdx.x; t < SCAN_V; t += blockDim.x) {
        int e = e0 + t * 4;
        if (e < N_EDGES) {
            iv4 d4 = *(const iv4*)(p.dst + e);
#pragma unroll
            for (int k = 0; k < 4; ++k) {
                int d = d4[k];
                if ((cbm[d >> 5] >> (d & 31)) & 1u) {
                    int idx = atomicAdd(&scnt, 1);
                    if (idx < R2CAP) { lbs[idx] = p.src[e + k]; lbd[idx] = d; }
                }
            }
        }
    }
    __syncthreads();
    int cnt = min(scnt, R2CAP);
    if (threadIdx.x == 0) p.c2[blockIdx.x] = cnt;
    if ((int)threadIdx.x < cnt) {
        p.s2[blockIdx.x * R2CAP + threadIdx.x] = lbs[threadIdx.x];
        p.d2[blockIdx.x * R2CAP + threadIdx.x] = lbd[threadIdx.x];
    }
}

// np2: rebuild marked set in LDS from (ptr, s2 regions); block 0 compacts
// marked -> map1 slots; marked words -> ndbm (distributed); scan: marked-dst
// edges -> (s1,d1) region + c1[b], srcs -> ndbm. Also zeroes agg1, out=b2.
__global__ void __launch_bounds__(SBLK) k_np2(P p) {
    __shared__ unsigned bm[3136];
    __shared__ int ls[R1CAP], ld[R1CAP];
    __shared__ int c2l[NBLK];
    __shared__ int scnt, slotc;
    for (int t = threadIdx.x; t < 3136; t += blockDim.x) bm[t] = 0u;
    for (int t = threadIdx.x; t < NBLK; t += blockDim.x) c2l[t] = p.c2[t];
    if (threadIdx.x == 0) { scnt = 0; slotc = 0; }
    __syncthreads();
    if (threadIdx.x < N_GRAPHS) {
        int c = p.ptr[threadIdx.x];
        atomicOr(&bm[c >> 5], 1u << (c & 31));
    }
    for (int r = threadIdx.x; r < NBLK; r += blockDim.x) {
        int n = c2l[r];
        for (int i = 0; i < n; ++i) {
            int s = p.s2[r * R2CAP + i];
            atomicOr(&bm[s >> 5], 1u << (s & 31));
        }
    }
    int gid = blockIdx.x * blockDim.x + threadIdx.x;
    int gst = gridDim.x * blockDim.x;
    for (int n = gid; n < (CAPS * IN_CH) / 4; n += gst)
        ((fv4*)p.agg1)[n] = (fv4){0.f, 0.f, 0.f, 0.f};
    for (int n = gid; n < (N_GRAPHS * OUT_CH) / 4; n += gst) {
        int c = (n * 4) & 127;
        ((fv4*)p.out)[n] = (fv4){ p.b2[c], p.b2[c + 1], p.b2[c + 2], p.b2[c + 3] };
    }
    __syncthreads();

    // marked words -> ndbm: distributed across blocks
    {
        int wpb = (BM_WORDS + NBLK - 1) / NBLK;
        for (int w = blockIdx.x * wpb + threadIdx.x;
             w < min((int)((blockIdx.x + 1) * wpb), BM_WORDS); w += blockDim.x) {
            unsigned word = bm[w];
            if (word) atomicOr(&p.ndbm[w], word);
        }
    }

    // block 0: compact marked nodes -> map1 slots (wave-aggregated, LDS counter;
    // slot order nondeterministic but bijective — map1 is the source of truth)
    if (blockIdx.x == 0) {
        int lane = threadIdx.x & 63;
        for (int w0 = 0; w0 < BM_WORDS; w0 += blockDim.x) {
            int w = w0 + threadIdx.x;
            unsigned word = (w < BM_WORDS) ? bm[w] : 0u;
            int c = __popc(word);
            int inc = c;
            for (int off = 1; off < 64; off <<= 1) {
                int t = __shfl_up(inc, off, 64);
                if (lane >= off) inc += t;
            }
            int total = __shfl(inc, 63, 64);
            int base = 0;
            if (total > 0) {
                if (lane == 63) base = atomicAdd(&slotc, total);
                base = __shfl(base, 63, 64);
                int slot = base + inc - c;
                unsigned ww = word;
                while (ww) {
                    int b = __ffs(ww) - 1; ww &= ww - 1;
                    int n = (w << 5) + b;
                    p.map1[n] = (slot < CAPS) ? slot : 0;
                    ++slot;
                }
            }
        }
    }

    // scan: marked-dst edges -> LDS buffers; srcs -> ndbm
    int e0 = blockIdx.x * SCAN_CHUNK;
    for (int t = threadIdx.x; t < SCAN_V; t += blockDim.x) {
        int e = e0 + t * 4;
        if (e < N_EDGES) {
            iv4 d4 = *(const iv4*)(p.dst + e);
#pragma unroll
            for (int k = 0; k < 4; ++k) {
                int d = d4[k];
                if ((bm[d >> 5] >> (d & 31)) & 1u) {
                    int s = p.src[e + k];
                    atomicOr(&p.ndbm[s >> 5], 1u << (s & 31));
                    int idx = atomicAdd(&scnt, 1);
                    if (idx < R1CAP) { ls[idx] = s; ld[idx] = d; }
                }
            }
        }
    }
    __syncthreads();
    int cnt = min(scnt, R1CAP);
    if (threadIdx.x == 0) p.c1[blockIdx.x] = cnt;
    for (int t = threadIdx.x; t < cnt; t += blockDim.x) {
        p.s1[blockIdx.x * R1CAP + t] = ls[t];
        p.d1[blockIdx.x * R1CAP + t] = ld[t];
    }
}

// p3: snapshot ndbm (cached); degree count only for dst in the needed set.
__global__ void __launch_bounds__(SBLK) k_p3(P p) {
    __shared__ unsigned nds[3136];
    for (int t = threadIdx.x; t < 3136 / 4; t += blockDim.x)
        ((iv4*)nds)[t] = ((const iv4*)p.ndbm)[t];
    __syncthreads();
    int e0 = blockIdx.x * SCAN_CHUNK;
    for (int t = threadIdx.x; t < SCAN_V; t += blockDim.x) {
        int e = e0 + t * 4;
        if (e < N_EDGES) {
            iv4 d4 = *(const iv4*)(p.dst + e);
#pragma unroll
            for (int k = 0; k < 4; ++k) {
                int d = d4[k];
                if ((nds[d >> 5] >> (d & 31)) & 1u) atomicAdd(&p.deg[d], 1u);
            }
        }
    }
}

// D: agg1[slot(dst)] += dis[src]*x[src] over list1 regions.
// 1024 blocks -> 4096 waves: 8 stripes per region (R23-validated tail fix).
__global__ void __launch_bounds__(256) k_D(P p) {
    int lane = threadIdx.x & 63;
    int g = lane >> 4;
    int c = lane & 15;
    int wid = blockIdx.x * (blockDim.x >> 6) + (threadIdx.x >> 6);
    int r = wid & (NBLK - 1);
    int sub = wid >> 9;                     // 0..7
    int c1r = p.c1[r];
    for (int i0 = sub * 4; i0 < c1r; i0 += 32) {
        int i = i0 + g;
        if (i < c1r) {
            int s = p.s1[r * R1CAP + i];
            int d = p.d1[r * R1CAP + i];
            int slot = p.map1[d];
            float w = rsqrtf((float)(1u + p.deg[s]));
            float xv = p.x[(size_t)s * IN_CH + c];
            atomicAdd(&p.agg1[(size_t)slot * IN_CH + c], w * xv);
        }
    }
}

// E item processor (R23-validated).
__device__ __forceinline__ void e_item(const P& p, const float* w1s,
                                       const float* b1s, const float* w2s,
                                       int lane, int c0, int c1v,
                                       int s, int d, int selfrow) {
    int slot = p.map1[s];
    float dis_s = rsqrtf((float)(1u + p.deg[s]));
    float dis_d = rsqrtf((float)(1u + p.deg[d]));
    float norm = dis_s * dis_d;
    float vc = 0.0f;
    if (lane < IN_CH)
        vc = dis_s * p.agg1[(size_t)slot * IN_CH + lane]
           + dis_s * dis_s * p.x[(size_t)s * IN_CH + lane];
    float h = b1s[lane];
#pragma unroll
    for (int c = 0; c < IN_CH; ++c)
        h += __shfl(vc, c, 64) * w1s[c * HID_CH + lane];
    h = fmaxf(h, 0.0f);
    float a0 = 0.0f, a1 = 0.0f;
#pragma unroll 8
    for (int j = 0; j < HID_CH; ++j) {
        float hv = __shfl(h, j, 64);
        a0 += hv * w2s[j * OUT_CH + lane];
        a1 += hv * w2s[j * OUT_CH + lane + 64];
    }
    a0 *= norm; a1 *= norm;
    if (selfrow >= 0) {
        atomicAdd(&p.out[selfrow * OUT_CH + lane], a0);
        atomicAdd(&p.out[selfrow * OUT_CH + lane + 64], a1);
    } else {
        unsigned long long b0 = __ballot(c0 == d);
        unsigned long long b1 = __ballot(c1v == d);
        while (b0) {
            int r = __ffsll((long long)b0) - 1; b0 &= b0 - 1;
            atomicAdd(&p.out[r * OUT_CH + lane], a0);
            atomicAdd(&p.out[r * OUT_CH + lane + 64], a1);
        }
        while (b1) {
            int r = __ffsll((long long)b1) - 1 + 64; b1 &= b1 - 1;
            atomicAdd(&p.out[r * OUT_CH + lane], a0);
            atomicAdd(&p.out[r * OUT_CH + lane + 64], a1);
        }
    }
}

// E: 1024 blocks -> 4096 waves; wave = (region u, stripe), items striped 8-way.
// Waves 0..127 also handle the 128 central self items.
__global__ void __launch_bounds__(256) k_E(P p) {
    __shared__ float w1s[IN_CH * HID_CH];
    __shared__ float b1s[HID_CH];
    __shared__ float w2s[HID_CH * OUT_CH];
    __shared__ int cent[128];
    for (int t = threadIdx.x; t < IN_CH * HID_CH; t += blockDim.x) w1s[t] = p.W1[t];
    if (threadIdx.x < HID_CH) b1s[threadIdx.x] = p.b1[threadIdx.x];
    for (int t = threadIdx.x; t < HID_CH * OUT_CH; t += blockDim.x) w2s[t] = p.W2[t];
    if (threadIdx.x < 128) cent[threadIdx.x] = p.ptr[threadIdx.x];
    __syncthreads();
    int lane = threadIdx.x & 63;
    int c0 = cent[lane];
    int c1v = cent[lane + 64];
    int wid = blockIdx.x * (blockDim.x >> 6) + (threadIdx.x >> 6);   // 0..4095
    int u = wid & (NBLK - 1);
    int stripe = wid >> 9;                  // 0..7
    int nE = p.c2[u];
    for (int i = stripe; i < nE; i += 8)
        e_item(p, w1s, b1s, w2s, lane, c0, c1v,
               p.s2[u * R2CAP + i], p.d2[u * R2CAP + i], -1);
    if (wid < N_GRAPHS)
        e_item(p, w1s, b1s, w2s, lane, c0, c1v, cent[wid], cent[wid], wid);
}

// ---------------- launch ----------------

extern "C" void kernel_launch(void* const* d_in, const int* in_sizes, int n_in,
                              void* d_out, int out_size, void* d_ws, size_t ws_size,
                              hipStream_t stream) {
    P p;
    p.x   = (const float*)d_in[0];          // fp32 (validated)
    const int* edge = (const int*)d_in[1];  // int32 (validated)
    p.src = edge;
    p.dst = edge + N_EDGES;
    p.ptr = (const int*)d_in[2];
    p.W1  = (const float*)d_in[3];
    p.b1  = (const float*)d_in[4];
    p.W2  = (const float*)d_in[5];
    p.b2  = (const float*)d_in[6];
    p.out = (float*)d_out;

    char* q = (char*)d_ws;
    auto alloc = [&](size_t bytes) {
        char* r = q; q += (bytes + 255) & ~size_t(255); return r;
    };
    p.deg  = (unsigned*)alloc((size_t)N_NODES * 4);
    p.map1 = (int*)     alloc((size_t)N_NODES * 4);
    p.s1   = (int*)     alloc((size_t)NBLK * R1CAP * 4);
    p.d1   = (int*)     alloc((size_t)NBLK * R1CAP * 4);
    p.c1   = (int*)     alloc((size_t)NBLK * 4);
    p.s2   = (int*)     alloc((size_t)NBLK * R2CAP * 4);
    p.d2   = (int*)     alloc((size_t)NBLK * R2CAP * 4);
    p.c2   = (int*)     alloc((size_t)NBLK * 4);
    p.agg1 = (float*)   alloc((size_t)CAPS * IN_CH * 4);
    p.ndbm = (unsigned*)alloc((size_t)BM_PAD * 4);

    hipLaunchKernelGGL(k_p1,  dim3(NBLK), dim3(SBLK), 0, stream, p);
    hipLaunchKernelGGL(k_np2, dim3(NBLK), dim3(SBLK), 0, stream, p);
    hipLaunchKernelGGL(k_p3,  dim3(NBLK), dim3(SBLK), 0, stream, p);
    hipLaunchKernelGGL(k_D,   dim3(1024), dim3(256), 0, stream, p);
    hipLaunchKernelGGL(k_E,   dim3(1024), dim3(256), 0, stream, p);
}